// Round 8
// baseline (890.797 us; speedup 1.0000x reference)
//
#include <hip/hip_runtime.h>
#include <math.h>

#define NBLK 256
#define THREADS 256
#define PTS 7  // 256*256*7 = 458752 >= 400000

struct SmallState {
    float meanf[3];
    float inv_sf;
    float Qf[12][3];
    double Qd[12][3];
};

// Device-global state. g_cnt/g_gen: barrier counter+generation (cnt returns to
// 0 after every barrier; gen is monotonic -> safe across graph replays).
__device__ SmallState g_sm;
__device__ double g_part[NBLK * 48];
__device__ int g_cnt = 0;
__device__ int g_gen = 0;

__device__ inline float waveReduceAdd(float v) {
#pragma unroll
    for (int off = 32; off > 0; off >>= 1) v += __shfl_down(v, off, 64);
    return v;
}

// Grid-wide barrier: proven fence/atomicAdd pattern from round 7, extended
// with a generation release. All NBLK blocks are co-resident (grid <= CUs).
__device__ inline void gridBarrier() {
    __syncthreads();
    if (threadIdx.x == 0) {
        __threadfence();  // publish this block's prior stores (device scope)
        int myGen = __hip_atomic_load(&g_gen, __ATOMIC_RELAXED,
                                      __HIP_MEMORY_SCOPE_AGENT);
        int prev = atomicAdd(&g_cnt, 1);
        if (prev == NBLK - 1) {
            __hip_atomic_store(&g_cnt, 0, __ATOMIC_RELAXED,
                               __HIP_MEMORY_SCOPE_AGENT);
            __threadfence();
            __hip_atomic_store(&g_gen, myGen + 1, __ATOMIC_RELEASE,
                               __HIP_MEMORY_SCOPE_AGENT);
        } else {
            while (__hip_atomic_load(&g_gen, __ATOMIC_ACQUIRE,
                                     __HIP_MEMORY_SCOPE_AGENT) == myGen)
                __builtin_amdgcn_s_sleep(1);
        }
    }
    __syncthreads();
}

// Serial f64 weighted-Kabsch tail (bit-identical math to rounds 4/7,
// absmax 0.0 verified). dsum[48] = {S[12], Tx[12], Ty[12], Tz[12]}.
__device__ void kabschUpdate(const double* __restrict__ dsum,
                             float* __restrict__ out, int it) {
    double S[12], Tv[12][3], Q[12][3];
    for (int i = 0; i < 12; i++) {
        S[i] = dsum[i];
        Tv[i][0] = dsum[12 + i];
        Tv[i][1] = dsum[24 + i];
        Tv[i][2] = dsum[36 + i];
        for (int c = 0; c < 3; c++) Q[i][c] = g_sm.Qd[i][c];
    }
    double n[12], wsum = 0;
    for (int i = 0; i < 12; i++) {
        n[i] = 1.0 / (S[i] + 1e-6);
        wsum += S[i] * n[i];
    }
    wsum = fmax(wsum, 1e-6);
    double cP[3] = {0, 0, 0}, cQ[3] = {0, 0, 0};
    for (int i = 0; i < 12; i++)
        for (int c = 0; c < 3; c++) {
            cP[c] += n[i] * Tv[i][c];
            cQ[c] += S[i] * n[i] * Q[i][c];
        }
    for (int c = 0; c < 3; c++) { cP[c] /= wsum; cQ[c] /= wsum; }

    double H[3][3] = {{0, 0, 0}, {0, 0, 0}, {0, 0, 0}};
    for (int i = 0; i < 12; i++) {
        double ta[3];
        for (int a = 0; a < 3; a++) ta[a] = n[i] * (Tv[i][a] - S[i] * cP[a]);
        for (int a = 0; a < 3; a++)
            for (int b = 0; b < 3; b++) H[a][b] += ta[a] * (Q[i][b] - cQ[b]);
    }
    for (int a = 0; a < 3; a++) H[a][a] += 1e-6;

    double A[3][3], V[3][3];
    for (int a = 0; a < 3; a++)
        for (int b = 0; b < 3; b++) {
            double s = 0;
            for (int k = 0; k < 3; k++) s += H[k][a] * H[k][b];
            A[a][b] = s;
            V[a][b] = (a == b) ? 1.0 : 0.0;
        }
    for (int sweep = 0; sweep < 8; sweep++) {
        for (int p = 0; p < 2; p++)
            for (int q = p + 1; q < 3; q++) {
                double apq = A[p][q];
                // skip converged rotations (|angle| ~ 1e-12 -> no-op)
                if (fabs(apq) < 1e-12 * (fabs(A[p][p]) + fabs(A[q][q]))) continue;
                double theta = (A[q][q] - A[p][p]) / (2.0 * apq);
                double t = copysign(1.0, theta) / (fabs(theta) + sqrt(theta * theta + 1.0));
                double c = 1.0 / sqrt(t * t + 1.0);
                double s = t * c;
                A[p][p] = A[p][p] - t * apq;
                A[q][q] = A[q][q] + t * apq;
                A[p][q] = 0; A[q][p] = 0;
                int r = 3 - p - q;
                double arp = A[r][p], arq = A[r][q];
                A[r][p] = A[p][r] = c * arp - s * arq;
                A[r][q] = A[q][r] = s * arp + c * arq;
                for (int k = 0; k < 3; k++) {
                    double vkp = V[k][p], vkq = V[k][q];
                    V[k][p] = c * vkp - s * vkq;
                    V[k][q] = s * vkp + c * vkq;
                }
            }
    }
    double U[3][3];
    for (int k = 0; k < 3; k++) {
        double sig = sqrt(fmax(A[k][k], 0.0));
        double u[3];
        for (int a = 0; a < 3; a++)
            u[a] = H[a][0] * V[0][k] + H[a][1] * V[1][k] + H[a][2] * V[2][k];
        double invsig = 1.0 / fmax(sig, 1e-30);
        for (int a = 0; a < 3; a++) U[a][k] = u[a] * invsig;
    }
    double R[3][3];
    for (int a = 0; a < 3; a++)
        for (int b = 0; b < 3; b++)
            R[a][b] = V[a][0] * U[b][0] + V[a][1] * U[b][1] + V[a][2] * U[b][2];
    double det = R[0][0] * (R[1][1] * R[2][2] - R[1][2] * R[2][1])
               - R[0][1] * (R[1][0] * R[2][2] - R[1][2] * R[2][0])
               + R[0][2] * (R[1][0] * R[2][1] - R[1][1] * R[2][0]);
    if (det < 0)
        for (int a = 0; a < 3; a++)
            for (int b = 0; b < 3; b++) R[a][b] = -R[a][b];
    double tr[3];
    for (int b = 0; b < 3; b++)
        tr[b] = cQ[b] - (cP[0] * R[0][b] + cP[1] * R[1][b] + cP[2] * R[2][b]);

    double res2 = 0;
    for (int i = 0; i < 12; i++) {
        double qn[3];
        for (int b = 0; b < 3; b++) {
            qn[b] = Q[i][0] * R[0][b] + Q[i][1] * R[1][b] + Q[i][2] * R[2][b] + tr[b];
            double diff = qn[b] - n[i] * Tv[i][b];
            res2 += diff * diff;
        }
        for (int b = 0; b < 3; b++) {
            g_sm.Qd[i][b] = qn[b];
            g_sm.Qf[i][b] = (float)qn[b];
        }
    }
    if (it == 9) {
        double rmsd = sqrt(res2 / 12.0 + 1e-6);
        out[0] = (float)(-10.0 * rmsd);
    }
}

__global__ void __launch_bounds__(THREADS)
k_all(const float* __restrict__ xyz, const float* __restrict__ zdna,
      float* __restrict__ out, int N) {
    const int tid = threadIdx.x, bid = blockIdx.x;
    const int gid = bid * THREADS + tid;
    const int gsz = NBLK * THREADS;
    const int wave = tid >> 6, lane = tid & 63;

    __shared__ double sh48[4][48];
    __shared__ double red[4][48];
    __shared__ double dsum[48];

    // ---- Phase 1: strided CA load into registers + column stats ----
    float px[PTS], py[PTS], pz[PTS];
    float s0 = 0, s1 = 0, s2 = 0, q0 = 0, q1 = 0, q2 = 0;
#pragma unroll
    for (int k = 0; k < PTS; k++) {
        int j = gid + k * gsz;
        px[k] = 0.0f; py[k] = 0.0f; pz[k] = 0.0f;
        if (j < N) {
            size_t base = (size_t)j * 81 + 3;
            float x = xyz[base + 0], y = xyz[base + 1], z = xyz[base + 2];
            px[k] = x; py[k] = y; pz[k] = z;
            s0 += x; s1 += y; s2 += z;
            q0 += x * x; q1 += y * y; q2 += z * z;
        }
    }
    {
        float v[6] = {s0, s1, s2, q0, q1, q2};
#pragma unroll
        for (int k = 0; k < 6; k++) v[k] = waveReduceAdd(v[k]);
        if (lane == 0) {
#pragma unroll
            for (int k = 0; k < 6; k++) sh48[wave][k] = (double)v[k];
        }
        __syncthreads();
        if (tid < 6)
            g_part[bid * 48 + tid] =
                sh48[0][tid] + sh48[1][tid] + sh48[2][tid] + sh48[3][tid];
    }
    gridBarrier();

    // ---- Phase 2 (block 0): mean/std finalize + zdna normalize ----
    if (bid == 0) {
        if (tid < 6) {
            double a0 = 0, a1 = 0, a2 = 0, a3 = 0;
            for (int b = 0; b < NBLK; b += 4) {
                a0 += g_part[(b + 0) * 48 + tid];
                a1 += g_part[(b + 1) * 48 + tid];
                a2 += g_part[(b + 2) * 48 + tid];
                a3 += g_part[(b + 3) * 48 + tid];
            }
            dsum[tid] = (a0 + a1) + (a2 + a3);
        }
        __syncthreads();
        if (tid == 0) {
            double mean[3], stdsum = 0;
            for (int c = 0; c < 3; c++) {
                mean[c] = dsum[c] / (double)N;
                double var = (dsum[3 + c] - (double)N * mean[c] * mean[c]) / (double)(N - 1);
                stdsum += sqrt(fmax(var, 0.0));
            }
            double sdev = fmax(stdsum / 3.0, 1e-6);
            double inv = 1.0 / sdev;
            for (int c = 0; c < 3; c++) g_sm.meanf[c] = (float)mean[c];
            g_sm.inv_sf = (float)inv;

            double z[12][3], zm[3] = {0, 0, 0};
            for (int i = 0; i < 12; i++)
                for (int c = 0; c < 3; c++) {
                    z[i][c] = (double)zdna[i * 3 + c];
                    zm[c] += z[i][c];
                }
            for (int c = 0; c < 3; c++) zm[c] /= 12.0;
            double zvar[3] = {0, 0, 0};
            for (int i = 0; i < 12; i++)
                for (int c = 0; c < 3; c++) {
                    z[i][c] -= zm[c];
                    zvar[c] += z[i][c] * z[i][c];
                }
            double zs = 0;
            for (int c = 0; c < 3; c++) zs += sqrt(zvar[c] / 11.0);
            zs = fmax(zs / 3.0, 1e-6);
            double zinv = 1.0 / zs;
            for (int i = 0; i < 12; i++)
                for (int c = 0; c < 3; c++) {
                    double q = z[i][c] * zinv;
                    g_sm.Qd[i][c] = q;
                    g_sm.Qf[i][c] = (float)q;
                }
        }
    }
    gridBarrier();

    // ---- normalize register-resident points ----
    {
        float mx = g_sm.meanf[0], my = g_sm.meanf[1], mz = g_sm.meanf[2];
        float inv = g_sm.inv_sf;
#pragma unroll
        for (int k = 0; k < PTS; k++) {
            px[k] = (px[k] - mx) * inv;
            py[k] = (py[k] - my) * inv;
            pz[k] = (pz[k] - mz) * inv;
        }
    }

    const float inv2s2 = 1.0f / 50.000001f;  // 1/(2*sigma^2+1e-6), sigma=5

    // ---- Phase 3: 10 soft-assign + Kabsch iterations, all in one launch ----
    for (int it = 0; it < 10; ++it) {
        float qx[12], qy[12], qz[12], qq[12];
#pragma unroll
        for (int i = 0; i < 12; i++) {
            qx[i] = g_sm.Qf[i][0];
            qy[i] = g_sm.Qf[i][1];
            qz[i] = g_sm.Qf[i][2];
            qq[i] = qx[i] * qx[i] + qy[i] * qy[i] + qz[i] * qz[i];
        }
        float S[12], Tx[12], Ty[12], Tz[12];
#pragma unroll
        for (int i = 0; i < 12; i++) { S[i] = 0; Tx[i] = 0; Ty[i] = 0; Tz[i] = 0; }
#pragma unroll
        for (int k = 0; k < PTS; k++) {
            if (gid + k * gsz < N) {
                float x = px[k], y = py[k], z = pz[k];
                float pp = x * x + y * y + z * z;
#pragma unroll
                for (int i = 0; i < 12; i++) {
                    float d2 = qq[i] + pp - 2.0f * (qx[i] * x + qy[i] * y + qz[i] * z);
                    d2 = fmaxf(d2, 0.0f);
                    float w = __expf(-d2 * inv2s2);
                    S[i] += w;
                    Tx[i] += w * x;
                    Ty[i] += w * y;
                    Tz[i] += w * z;
                }
            }
        }
        float acc[48];
#pragma unroll
        for (int i = 0; i < 12; i++) {
            acc[i] = S[i]; acc[12 + i] = Tx[i]; acc[24 + i] = Ty[i]; acc[36 + i] = Tz[i];
        }
#pragma unroll
        for (int k = 0; k < 48; k++) acc[k] = waveReduceAdd(acc[k]);
        if (lane == 0) {
#pragma unroll
            for (int k = 0; k < 48; k++) sh48[wave][k] = (double)acc[k];
        }
        __syncthreads();
        if (tid < 48)
            g_part[bid * 48 + tid] =
                sh48[0][tid] + sh48[1][tid] + sh48[2][tid] + sh48[3][tid];
        __syncthreads();  // sh48 reused next iteration
        gridBarrier();

        if (bid == 0) {
            if (tid < 192) {
                int col = tid % 48, seg = tid / 48;
                int b0 = seg * 64;
                double a0 = 0, a1 = 0, a2 = 0, a3 = 0;
                for (int b = b0; b < b0 + 64; b += 4) {
                    a0 += g_part[(b + 0) * 48 + col];
                    a1 += g_part[(b + 1) * 48 + col];
                    a2 += g_part[(b + 2) * 48 + col];
                    a3 += g_part[(b + 3) * 48 + col];
                }
                red[seg][col] = (a0 + a1) + (a2 + a3);
            }
            __syncthreads();
            if (tid < 48)
                dsum[tid] = (red[0][tid] + red[1][tid]) + (red[2][tid] + red[3][tid]);
            __syncthreads();
            if (tid == 0) kabschUpdate(dsum, out, it);
        }
        gridBarrier();
    }
}

extern "C" void kernel_launch(void* const* d_in, const int* in_sizes, int n_in,
                              void* d_out, int out_size, void* d_ws, size_t ws_size,
                              hipStream_t stream) {
    (void)d_ws; (void)ws_size;
    const float* xyz = (const float*)d_in[0];
    const float* zdna = (const float*)d_in[1];
    int N = in_sizes[0] / 81;  // CA at atom index 1 of 27
    float* out = (float*)d_out;

    hipLaunchKernelGGL(k_all, dim3(NBLK), dim3(THREADS), 0, stream,
                       xyz, zdna, out, N);
}

// Round 9
// 858.274 us; speedup vs baseline: 1.0379x; 1.0379x over previous
//
#include <hip/hip_runtime.h>
#include <math.h>

#define NBLK 256
#define THREADS 256
#define PTS 7   // 256*256*7 = 458752 >= 400000
#define FS 16   // flag stride in ints -> one 64B line per flag

struct SmallState {
    float meanf[3];
    float inv_sf;
    float Qf[12][3];
    double Qd[12][3];
};

// Device-global state. g_flag/g_gen are MONOTONIC forever (never reset):
// each call reads base=g_gen at entry; round r uses value base+r. Safe across
// graph replays, no cross-call races (stream-serialized launches).
__device__ SmallState g_sm;
__device__ double g_part[NBLK * 48];
__device__ int g_flag[NBLK * FS];  // zero at module load
__device__ int g_gen = 0;

__device__ inline float waveReduceAdd(float v) {
#pragma unroll
    for (int off = 32; off > 0; off >>= 1) v += __shfl_down(v, off, 64);
    return v;
}

__device__ inline int loadAcq(int* p) {
    return __hip_atomic_load(p, __ATOMIC_ACQUIRE, __HIP_MEMORY_SCOPE_AGENT);
}
__device__ inline void storeRel(int* p, int v) {
    __hip_atomic_store(p, v, __ATOMIC_RELEASE, __HIP_MEMORY_SCOPE_AGENT);
}
__device__ inline int loadRlx(int* p) {
    return __hip_atomic_load(p, __ATOMIC_RELAXED, __HIP_MEMORY_SCOPE_AGENT);
}

// Serial f64 weighted-Kabsch tail (bit-identical to rounds 4/7/8, absmax 0.0).
__device__ void kabschUpdate(const double* __restrict__ dsum,
                             float* __restrict__ out, int it) {
    double S[12], Tv[12][3], Q[12][3];
    for (int i = 0; i < 12; i++) {
        S[i] = dsum[i];
        Tv[i][0] = dsum[12 + i];
        Tv[i][1] = dsum[24 + i];
        Tv[i][2] = dsum[36 + i];
        for (int c = 0; c < 3; c++) Q[i][c] = g_sm.Qd[i][c];
    }
    double n[12], wsum = 0;
    for (int i = 0; i < 12; i++) {
        n[i] = 1.0 / (S[i] + 1e-6);
        wsum += S[i] * n[i];
    }
    wsum = fmax(wsum, 1e-6);
    double cP[3] = {0, 0, 0}, cQ[3] = {0, 0, 0};
    for (int i = 0; i < 12; i++)
        for (int c = 0; c < 3; c++) {
            cP[c] += n[i] * Tv[i][c];
            cQ[c] += S[i] * n[i] * Q[i][c];
        }
    for (int c = 0; c < 3; c++) { cP[c] /= wsum; cQ[c] /= wsum; }

    double H[3][3] = {{0, 0, 0}, {0, 0, 0}, {0, 0, 0}};
    for (int i = 0; i < 12; i++) {
        double ta[3];
        for (int a = 0; a < 3; a++) ta[a] = n[i] * (Tv[i][a] - S[i] * cP[a]);
        for (int a = 0; a < 3; a++)
            for (int b = 0; b < 3; b++) H[a][b] += ta[a] * (Q[i][b] - cQ[b]);
    }
    for (int a = 0; a < 3; a++) H[a][a] += 1e-6;

    double A[3][3], V[3][3];
    for (int a = 0; a < 3; a++)
        for (int b = 0; b < 3; b++) {
            double s = 0;
            for (int k = 0; k < 3; k++) s += H[k][a] * H[k][b];
            A[a][b] = s;
            V[a][b] = (a == b) ? 1.0 : 0.0;
        }
    for (int sweep = 0; sweep < 8; sweep++) {
        for (int p = 0; p < 2; p++)
            for (int q = p + 1; q < 3; q++) {
                double apq = A[p][q];
                if (fabs(apq) < 1e-12 * (fabs(A[p][p]) + fabs(A[q][q]))) continue;
                double theta = (A[q][q] - A[p][p]) / (2.0 * apq);
                double t = copysign(1.0, theta) / (fabs(theta) + sqrt(theta * theta + 1.0));
                double c = 1.0 / sqrt(t * t + 1.0);
                double s = t * c;
                A[p][p] = A[p][p] - t * apq;
                A[q][q] = A[q][q] + t * apq;
                A[p][q] = 0; A[q][p] = 0;
                int r = 3 - p - q;
                double arp = A[r][p], arq = A[r][q];
                A[r][p] = A[p][r] = c * arp - s * arq;
                A[r][q] = A[q][r] = s * arp + c * arq;
                for (int k = 0; k < 3; k++) {
                    double vkp = V[k][p], vkq = V[k][q];
                    V[k][p] = c * vkp - s * vkq;
                    V[k][q] = s * vkp + c * vkq;
                }
            }
    }
    double U[3][3];
    for (int k = 0; k < 3; k++) {
        double sig = sqrt(fmax(A[k][k], 0.0));
        double u[3];
        for (int a = 0; a < 3; a++)
            u[a] = H[a][0] * V[0][k] + H[a][1] * V[1][k] + H[a][2] * V[2][k];
        double invsig = 1.0 / fmax(sig, 1e-30);
        for (int a = 0; a < 3; a++) U[a][k] = u[a] * invsig;
    }
    double R[3][3];
    for (int a = 0; a < 3; a++)
        for (int b = 0; b < 3; b++)
            R[a][b] = V[a][0] * U[b][0] + V[a][1] * U[b][1] + V[a][2] * U[b][2];
    double det = R[0][0] * (R[1][1] * R[2][2] - R[1][2] * R[2][1])
               - R[0][1] * (R[1][0] * R[2][2] - R[1][2] * R[2][0])
               + R[0][2] * (R[1][0] * R[2][1] - R[1][1] * R[2][0]);
    if (det < 0)
        for (int a = 0; a < 3; a++)
            for (int b = 0; b < 3; b++) R[a][b] = -R[a][b];
    double tr[3];
    for (int b = 0; b < 3; b++)
        tr[b] = cQ[b] - (cP[0] * R[0][b] + cP[1] * R[1][b] + cP[2] * R[2][b]);

    double res2 = 0;
    for (int i = 0; i < 12; i++) {
        double qn[3];
        for (int b = 0; b < 3; b++) {
            qn[b] = Q[i][0] * R[0][b] + Q[i][1] * R[1][b] + Q[i][2] * R[2][b] + tr[b];
            double diff = qn[b] - n[i] * Tv[i][b];
            res2 += diff * diff;
        }
        for (int b = 0; b < 3; b++) {
            g_sm.Qd[i][b] = qn[b];
            g_sm.Qf[i][b] = (float)qn[b];
        }
    }
    if (it == 9) {
        double rmsd = sqrt(res2 / 12.0 + 1e-6);
        out[0] = (float)(-10.0 * rmsd);
    }
}

__global__ void __launch_bounds__(THREADS)
k_all(const float* __restrict__ xyz, const float* __restrict__ zdna,
      float* __restrict__ out, int N) {
    const int tid = threadIdx.x, bid = blockIdx.x;
    const int gid = bid * THREADS + tid;
    const int gsz = NBLK * THREADS;
    const int wave = tid >> 6, lane = tid & 63;

    __shared__ int s_base;
    __shared__ double sh48[4][48];
    __shared__ double red[4][48];
    __shared__ double dsum[48];

    // All blocks read base BEFORE block 0's first release (which awaits all
    // arrivals, each of which follows this read) -> all agree on base.
    if (tid == 0) s_base = loadRlx(&g_gen);
    __syncthreads();
    const int base = s_base;

    // ---- Phase 1: strided CA load into registers + column stats ----
    float px[PTS], py[PTS], pz[PTS];
    float s0 = 0, s1 = 0, s2 = 0, q0 = 0, q1 = 0, q2 = 0;
#pragma unroll
    for (int k = 0; k < PTS; k++) {
        int j = gid + k * gsz;
        px[k] = 0.0f; py[k] = 0.0f; pz[k] = 0.0f;
        if (j < N) {
            size_t b = (size_t)j * 81 + 3;
            float x = xyz[b + 0], y = xyz[b + 1], z = xyz[b + 2];
            px[k] = x; py[k] = y; pz[k] = z;
            s0 += x; s1 += y; s2 += z;
            q0 += x * x; q1 += y * y; q2 += z * z;
        }
    }
    {
        float v[6] = {s0, s1, s2, q0, q1, q2};
#pragma unroll
        for (int k = 0; k < 6; k++) v[k] = waveReduceAdd(v[k]);
        if (lane == 0) {
#pragma unroll
            for (int k = 0; k < 6; k++) sh48[wave][k] = (double)v[k];
        }
        __syncthreads();
        if (tid < 6)
            g_part[bid * 48 + tid] =
                sh48[0][tid] + sh48[1][tid] + sh48[2][tid] + sh48[3][tid];
        __syncthreads();
    }

    // ---- Round 1: stats arrival -> block0 init -> release ----
    if (bid == 0) {
        if (tid < NBLK - 1)
            while (loadAcq(&g_flag[(tid + 1) * FS]) < base + 1)
                __builtin_amdgcn_s_sleep(2);
        __syncthreads();
        __threadfence();
        if (tid < 6) {
            double a0 = 0, a1 = 0, a2 = 0, a3 = 0;
            for (int b = 0; b < NBLK; b += 4) {
                a0 += g_part[(b + 0) * 48 + tid];
                a1 += g_part[(b + 1) * 48 + tid];
                a2 += g_part[(b + 2) * 48 + tid];
                a3 += g_part[(b + 3) * 48 + tid];
            }
            dsum[tid] = (a0 + a1) + (a2 + a3);
        }
        __syncthreads();
        if (tid == 0) {
            double mean[3], stdsum = 0;
            for (int c = 0; c < 3; c++) {
                mean[c] = dsum[c] / (double)N;
                double var = (dsum[3 + c] - (double)N * mean[c] * mean[c]) / (double)(N - 1);
                stdsum += sqrt(fmax(var, 0.0));
            }
            double sdev = fmax(stdsum / 3.0, 1e-6);
            double inv = 1.0 / sdev;
            for (int c = 0; c < 3; c++) g_sm.meanf[c] = (float)mean[c];
            g_sm.inv_sf = (float)inv;

            double z[12][3], zm[3] = {0, 0, 0};
            for (int i = 0; i < 12; i++)
                for (int c = 0; c < 3; c++) {
                    z[i][c] = (double)zdna[i * 3 + c];
                    zm[c] += z[i][c];
                }
            for (int c = 0; c < 3; c++) zm[c] /= 12.0;
            double zvar[3] = {0, 0, 0};
            for (int i = 0; i < 12; i++)
                for (int c = 0; c < 3; c++) {
                    z[i][c] -= zm[c];
                    zvar[c] += z[i][c] * z[i][c];
                }
            double zs = 0;
            for (int c = 0; c < 3; c++) zs += sqrt(zvar[c] / 11.0);
            zs = fmax(zs / 3.0, 1e-6);
            double zinv = 1.0 / zs;
            for (int i = 0; i < 12; i++)
                for (int c = 0; c < 3; c++) {
                    double q = z[i][c] * zinv;
                    g_sm.Qd[i][c] = q;
                    g_sm.Qf[i][c] = (float)q;
                }
            __threadfence();
            storeRel(&g_gen, base + 1);
        }
        __syncthreads();
    } else {
        if (tid == 0) {
            __threadfence();
            storeRel(&g_flag[bid * FS], base + 1);
            while (loadAcq(&g_gen) < base + 1) __builtin_amdgcn_s_sleep(2);
        }
        __syncthreads();
    }

    // ---- normalize register-resident points ----
    {
        float mx = g_sm.meanf[0], my = g_sm.meanf[1], mz = g_sm.meanf[2];
        float inv = g_sm.inv_sf;
#pragma unroll
        for (int k = 0; k < PTS; k++) {
            px[k] = (px[k] - mx) * inv;
            py[k] = (py[k] - my) * inv;
            pz[k] = (pz[k] - mz) * inv;
        }
    }

    const float inv2s2 = 1.0f / 50.000001f;  // 1/(2*sigma^2+1e-6), sigma=5

    // ---- Rounds 2..11: 10 soft-assign + Kabsch iterations ----
    for (int it = 0; it < 10; ++it) {
        const int tgt = base + 2 + it;
        float qx[12], qy[12], qz[12], qq[12];
#pragma unroll
        for (int i = 0; i < 12; i++) {
            qx[i] = g_sm.Qf[i][0];
            qy[i] = g_sm.Qf[i][1];
            qz[i] = g_sm.Qf[i][2];
            qq[i] = qx[i] * qx[i] + qy[i] * qy[i] + qz[i] * qz[i];
        }
        float S[12], Tx[12], Ty[12], Tz[12];
#pragma unroll
        for (int i = 0; i < 12; i++) { S[i] = 0; Tx[i] = 0; Ty[i] = 0; Tz[i] = 0; }
#pragma unroll
        for (int k = 0; k < PTS; k++) {
            if (gid + k * gsz < N) {
                float x = px[k], y = py[k], z = pz[k];
                float pp = x * x + y * y + z * z;
#pragma unroll
                for (int i = 0; i < 12; i++) {
                    float d2 = qq[i] + pp - 2.0f * (qx[i] * x + qy[i] * y + qz[i] * z);
                    d2 = fmaxf(d2, 0.0f);
                    float w = __expf(-d2 * inv2s2);
                    S[i] += w;
                    Tx[i] += w * x;
                    Ty[i] += w * y;
                    Tz[i] += w * z;
                }
            }
        }
        float acc[48];
#pragma unroll
        for (int i = 0; i < 12; i++) {
            acc[i] = S[i]; acc[12 + i] = Tx[i]; acc[24 + i] = Ty[i]; acc[36 + i] = Tz[i];
        }
#pragma unroll
        for (int k = 0; k < 48; k++) acc[k] = waveReduceAdd(acc[k]);
        if (lane == 0) {
#pragma unroll
            for (int k = 0; k < 48; k++) sh48[wave][k] = (double)acc[k];
        }
        __syncthreads();
        if (tid < 48)
            g_part[bid * 48 + tid] =
                sh48[0][tid] + sh48[1][tid] + sh48[2][tid] + sh48[3][tid];
        __syncthreads();

        if (bid == 0) {
            if (tid < NBLK - 1)
                while (loadAcq(&g_flag[(tid + 1) * FS]) < tgt)
                    __builtin_amdgcn_s_sleep(2);
            __syncthreads();
            __threadfence();
            if (tid < 192) {
                int col = tid % 48, seg = tid / 48;
                int b0 = seg * 64;
                double a0 = 0, a1 = 0, a2 = 0, a3 = 0;
                for (int b = b0; b < b0 + 64; b += 4) {
                    a0 += g_part[(b + 0) * 48 + col];
                    a1 += g_part[(b + 1) * 48 + col];
                    a2 += g_part[(b + 2) * 48 + col];
                    a3 += g_part[(b + 3) * 48 + col];
                }
                red[seg][col] = (a0 + a1) + (a2 + a3);
            }
            __syncthreads();
            if (tid < 48)
                dsum[tid] = (red[0][tid] + red[1][tid]) + (red[2][tid] + red[3][tid]);
            __syncthreads();
            if (tid == 0) {
                kabschUpdate(dsum, out, it);
                __threadfence();
                storeRel(&g_gen, tgt);
            }
            __syncthreads();
        } else {
            if (tid == 0) {
                __threadfence();
                storeRel(&g_flag[bid * FS], tgt);
                while (loadAcq(&g_gen) < tgt) __builtin_amdgcn_s_sleep(2);
            }
            __syncthreads();
        }
    }
}

extern "C" void kernel_launch(void* const* d_in, const int* in_sizes, int n_in,
                              void* d_out, int out_size, void* d_ws, size_t ws_size,
                              hipStream_t stream) {
    (void)d_ws; (void)ws_size;
    const float* xyz = (const float*)d_in[0];
    const float* zdna = (const float*)d_in[1];
    int N = in_sizes[0] / 81;  // CA at atom index 1 of 27
    float* out = (float*)d_out;

    hipLaunchKernelGGL(k_all, dim3(NBLK), dim3(THREADS), 0, stream,
                       xyz, zdna, out, N);
}

// Round 10
// 464.366 us; speedup vs baseline: 1.9183x; 1.8483x over previous
//
#include <hip/hip_runtime.h>
#include <math.h>

#define NBLK 256
#define THREADS 256
#define PTS 7      // 256*256*7 = 458752 >= 400000
#define NSHARD 8   // cross-block sum shards (32 adds per address)
#define NBAR 11    // 1 stats + 10 iterations
#define CPAD 16    // counter pad: one 64B line per counter

// Cross-block shared state. Accessed ONLY via sc1 (agent-scope) atomics/loads/
// stores -> no L2-cached copies anywhere -> no staleness, no invalidate storms.
// g_cnt is monotonic forever (never reset) -> safe across graph replays.
__device__ double g_slot[NBLK][8];          // stats per-block slots (64B rows)
__device__ double g_acc[10][NSHARD][48];    // per-iteration sharded accumulators
__device__ int g_cnt[NBAR * CPAD];          // arrival counters (monotonic)

__device__ inline float waveReduceAdd(float v) {
#pragma unroll
    for (int off = 32; off > 0; off >>= 1) v += __shfl_down(v, off, 64);
    return v;
}

__device__ inline int loadRlxI(int* p) {
    return __hip_atomic_load(p, __ATOMIC_RELAXED, __HIP_MEMORY_SCOPE_AGENT);
}
__device__ inline int loadAcqI(int* p) {
    return __hip_atomic_load(p, __ATOMIC_ACQUIRE, __HIP_MEMORY_SCOPE_AGENT);
}
__device__ inline double loadRlxD(double* p) {
    return __hip_atomic_load(p, __ATOMIC_RELAXED, __HIP_MEMORY_SCOPE_AGENT);
}
__device__ inline void storeRlxD(double* p, double v) {
    __hip_atomic_store(p, v, __ATOMIC_RELAXED, __HIP_MEMORY_SCOPE_AGENT);
}

// Thread-0-only arrival barrier. Caller guarantees this wave's prior sc1
// stores/atomics are program-order-before (threadfence drains vmcnt).
// Relaxed poll (no invalidate) + single acquire load at the end.
__device__ inline void arriveAndWait(int slot, int target) {
    __threadfence();
    atomicAdd(&g_cnt[slot * CPAD], 1);
    while (loadRlxI(&g_cnt[slot * CPAD]) < target) __builtin_amdgcn_s_sleep(8);
    (void)loadAcqI(&g_cnt[slot * CPAD]);
}

// Serial f64 weighted-Kabsch (bit-identical math to rounds 4/7/8/9, absmax
// 0.0). Operates on LDS state; runs redundantly in thread 0 of EVERY block.
__device__ void kabschUpdate(const double* __restrict__ dsum,
                             double (*Qd)[3], float (*Qf)[3],
                             float* __restrict__ out, int it, int writeOut) {
    double S[12], Tv[12][3], Q[12][3];
    for (int i = 0; i < 12; i++) {
        S[i] = dsum[i];
        Tv[i][0] = dsum[12 + i];
        Tv[i][1] = dsum[24 + i];
        Tv[i][2] = dsum[36 + i];
        for (int c = 0; c < 3; c++) Q[i][c] = Qd[i][c];
    }
    double n[12], wsum = 0;
    for (int i = 0; i < 12; i++) {
        n[i] = 1.0 / (S[i] + 1e-6);
        wsum += S[i] * n[i];
    }
    wsum = fmax(wsum, 1e-6);
    double cP[3] = {0, 0, 0}, cQ[3] = {0, 0, 0};
    for (int i = 0; i < 12; i++)
        for (int c = 0; c < 3; c++) {
            cP[c] += n[i] * Tv[i][c];
            cQ[c] += S[i] * n[i] * Q[i][c];
        }
    for (int c = 0; c < 3; c++) { cP[c] /= wsum; cQ[c] /= wsum; }

    double H[3][3] = {{0, 0, 0}, {0, 0, 0}, {0, 0, 0}};
    for (int i = 0; i < 12; i++) {
        double ta[3];
        for (int a = 0; a < 3; a++) ta[a] = n[i] * (Tv[i][a] - S[i] * cP[a]);
        for (int a = 0; a < 3; a++)
            for (int b = 0; b < 3; b++) H[a][b] += ta[a] * (Q[i][b] - cQ[b]);
    }
    for (int a = 0; a < 3; a++) H[a][a] += 1e-6;

    double A[3][3], V[3][3];
    for (int a = 0; a < 3; a++)
        for (int b = 0; b < 3; b++) {
            double s = 0;
            for (int k = 0; k < 3; k++) s += H[k][a] * H[k][b];
            A[a][b] = s;
            V[a][b] = (a == b) ? 1.0 : 0.0;
        }
    for (int sweep = 0; sweep < 8; sweep++) {
        for (int p = 0; p < 2; p++)
            for (int q = p + 1; q < 3; q++) {
                double apq = A[p][q];
                if (fabs(apq) < 1e-12 * (fabs(A[p][p]) + fabs(A[q][q]))) continue;
                double theta = (A[q][q] - A[p][p]) / (2.0 * apq);
                double t = copysign(1.0, theta) / (fabs(theta) + sqrt(theta * theta + 1.0));
                double c = 1.0 / sqrt(t * t + 1.0);
                double s = t * c;
                A[p][p] = A[p][p] - t * apq;
                A[q][q] = A[q][q] + t * apq;
                A[p][q] = 0; A[q][p] = 0;
                int r = 3 - p - q;
                double arp = A[r][p], arq = A[r][q];
                A[r][p] = A[p][r] = c * arp - s * arq;
                A[r][q] = A[q][r] = s * arp + c * arq;
                for (int k = 0; k < 3; k++) {
                    double vkp = V[k][p], vkq = V[k][q];
                    V[k][p] = c * vkp - s * vkq;
                    V[k][q] = s * vkp + c * vkq;
                }
            }
    }
    double U[3][3];
    for (int k = 0; k < 3; k++) {
        double sig = sqrt(fmax(A[k][k], 0.0));
        double u[3];
        for (int a = 0; a < 3; a++)
            u[a] = H[a][0] * V[0][k] + H[a][1] * V[1][k] + H[a][2] * V[2][k];
        double invsig = 1.0 / fmax(sig, 1e-30);
        for (int a = 0; a < 3; a++) U[a][k] = u[a] * invsig;
    }
    double R[3][3];
    for (int a = 0; a < 3; a++)
        for (int b = 0; b < 3; b++)
            R[a][b] = V[a][0] * U[b][0] + V[a][1] * U[b][1] + V[a][2] * U[b][2];
    double det = R[0][0] * (R[1][1] * R[2][2] - R[1][2] * R[2][1])
               - R[0][1] * (R[1][0] * R[2][2] - R[1][2] * R[2][0])
               + R[0][2] * (R[1][0] * R[2][1] - R[1][1] * R[2][0]);
    if (det < 0)
        for (int a = 0; a < 3; a++)
            for (int b = 0; b < 3; b++) R[a][b] = -R[a][b];
    double tr[3];
    for (int b = 0; b < 3; b++)
        tr[b] = cQ[b] - (cP[0] * R[0][b] + cP[1] * R[1][b] + cP[2] * R[2][b]);

    double res2 = 0;
    for (int i = 0; i < 12; i++) {
        double qn[3];
        for (int b = 0; b < 3; b++) {
            qn[b] = Q[i][0] * R[0][b] + Q[i][1] * R[1][b] + Q[i][2] * R[2][b] + tr[b];
            double diff = qn[b] - n[i] * Tv[i][b];
            res2 += diff * diff;
        }
        for (int b = 0; b < 3; b++) {
            Qd[i][b] = qn[b];
            Qf[i][b] = (float)qn[b];
        }
    }
    if (writeOut && it == 9) {
        double rmsd = sqrt(res2 / 12.0 + 1e-6);
        out[0] = (float)(-10.0 * rmsd);
    }
}

__global__ void __launch_bounds__(THREADS)
k_all(const float* __restrict__ xyz, const float* __restrict__ zdna,
      float* __restrict__ out, int N) {
    const int tid = threadIdx.x, bid = blockIdx.x;
    const int gid = bid * THREADS + tid;
    const int gsz = NBLK * THREADS;
    const int wave = tid >> 6, lane = tid & 63;

    __shared__ int s_base;
    __shared__ double sh48[4][48];
    __shared__ double red8[8][6];
    __shared__ double dsumL[48];
    __shared__ double QdL[12][3];
    __shared__ float QfL[12][3];
    __shared__ float s_mean[3], s_inv;

    // Base for monotonic counters: g_cnt[last] can't be incremented until all
    // blocks pass barriers 0..9, each of which follows every block's entry
    // read -> this read returns the pristine pre-call value in every block.
    if (tid == 0) s_base = loadRlxI(&g_cnt[(NBAR - 1) * CPAD]);
    __syncthreads();
    const int target = s_base + NBLK;

    // ---- Phase 1: strided CA load into registers + column stats ----
    float px[PTS], py[PTS], pz[PTS];
    float s0 = 0, s1 = 0, s2 = 0, q0 = 0, q1 = 0, q2 = 0;
#pragma unroll
    for (int k = 0; k < PTS; k++) {
        int j = gid + k * gsz;
        px[k] = 0.0f; py[k] = 0.0f; pz[k] = 0.0f;
        if (j < N) {
            size_t b = (size_t)j * 81 + 3;
            float x = xyz[b + 0], y = xyz[b + 1], z = xyz[b + 2];
            px[k] = x; py[k] = y; pz[k] = z;
            s0 += x; s1 += y; s2 += z;
            q0 += x * x; q1 += y * y; q2 += z * z;
        }
    }
    {
        float v[6] = {s0, s1, s2, q0, q1, q2};
#pragma unroll
        for (int k = 0; k < 6; k++) v[k] = waveReduceAdd(v[k]);
        if (lane == 0) {
#pragma unroll
            for (int k = 0; k < 6; k++) sh48[wave][k] = (double)v[k];
        }
        __syncthreads();
        // wave 0 only below (tid<6, tid<15, tid==0) -> thread 0's threadfence
        // (vmcnt drain) covers all these sc1 stores.
        if (tid < 6)
            storeRlxD(&g_slot[bid][tid],
                      sh48[0][tid] + sh48[1][tid] + sh48[2][tid] + sh48[3][tid]);
        // Zero this call's shard accumulators (3840 doubles over 256 blocks).
        if (tid < 15) {
            double* accFlat = &g_acc[0][0][0];
            storeRlxD(&accFlat[bid * 15 + tid], 0.0);
        }
        if (tid == 0) arriveAndWait(0, target);
        __syncthreads();
    }

    // ---- Phase 2 (EVERY block, redundant): mean/std + zdna normalize ----
    {
        if (tid < 48) {
            int col = tid % 6, seg = tid / 6;  // 8 segs x 32 blocks
            double a0 = 0, a1 = 0;
            for (int b = seg * 32; b < seg * 32 + 32; b += 2) {
                a0 += loadRlxD(&g_slot[b][col]);
                a1 += loadRlxD(&g_slot[b + 1][col]);
            }
            red8[seg][col] = a0 + a1;
        }
        __syncthreads();
        if (tid == 0) {
            double tot[6];
            for (int c = 0; c < 6; c++) {
                double s = 0;
                for (int g = 0; g < 8; g++) s += red8[g][c];
                tot[c] = s;
            }
            double mean[3], stdsum = 0;
            for (int c = 0; c < 3; c++) {
                mean[c] = tot[c] / (double)N;
                double var = (tot[3 + c] - (double)N * mean[c] * mean[c]) / (double)(N - 1);
                stdsum += sqrt(fmax(var, 0.0));
            }
            double sdev = fmax(stdsum / 3.0, 1e-6);
            s_mean[0] = (float)mean[0];
            s_mean[1] = (float)mean[1];
            s_mean[2] = (float)mean[2];
            s_inv = (float)(1.0 / sdev);

            double z[12][3], zm[3] = {0, 0, 0};
            for (int i = 0; i < 12; i++)
                for (int c = 0; c < 3; c++) {
                    z[i][c] = (double)zdna[i * 3 + c];
                    zm[c] += z[i][c];
                }
            for (int c = 0; c < 3; c++) zm[c] /= 12.0;
            double zvar[3] = {0, 0, 0};
            for (int i = 0; i < 12; i++)
                for (int c = 0; c < 3; c++) {
                    z[i][c] -= zm[c];
                    zvar[c] += z[i][c] * z[i][c];
                }
            double zs = 0;
            for (int c = 0; c < 3; c++) zs += sqrt(zvar[c] / 11.0);
            zs = fmax(zs / 3.0, 1e-6);
            double zinv = 1.0 / zs;
            for (int i = 0; i < 12; i++)
                for (int c = 0; c < 3; c++) {
                    double q = z[i][c] * zinv;
                    QdL[i][c] = q;
                    QfL[i][c] = (float)q;
                }
        }
        __syncthreads();
    }

    // ---- normalize register-resident points ----
    {
        float mx = s_mean[0], my = s_mean[1], mz = s_mean[2];
        float inv = s_inv;
#pragma unroll
        for (int k = 0; k < PTS; k++) {
            px[k] = (px[k] - mx) * inv;
            py[k] = (py[k] - my) * inv;
            pz[k] = (pz[k] - mz) * inv;
        }
    }

    const float inv2s2 = 1.0f / 50.000001f;  // 1/(2*sigma^2+1e-6), sigma=5
    const int myShard = bid % NSHARD;

    // ---- 10 iterations, ONE barrier each ----
    for (int it = 0; it < 10; ++it) {
        float qx[12], qy[12], qz[12], qq[12];
#pragma unroll
        for (int i = 0; i < 12; i++) {
            qx[i] = QfL[i][0];
            qy[i] = QfL[i][1];
            qz[i] = QfL[i][2];
            qq[i] = qx[i] * qx[i] + qy[i] * qy[i] + qz[i] * qz[i];
        }
        float S[12], Tx[12], Ty[12], Tz[12];
#pragma unroll
        for (int i = 0; i < 12; i++) { S[i] = 0; Tx[i] = 0; Ty[i] = 0; Tz[i] = 0; }
#pragma unroll
        for (int k = 0; k < PTS; k++) {
            if (gid + k * gsz < N) {
                float x = px[k], y = py[k], z = pz[k];
                float pp = x * x + y * y + z * z;
#pragma unroll
                for (int i = 0; i < 12; i++) {
                    float d2 = qq[i] + pp - 2.0f * (qx[i] * x + qy[i] * y + qz[i] * z);
                    d2 = fmaxf(d2, 0.0f);
                    float w = __expf(-d2 * inv2s2);
                    S[i] += w;
                    Tx[i] += w * x;
                    Ty[i] += w * y;
                    Tz[i] += w * z;
                }
            }
        }
        float acc[48];
#pragma unroll
        for (int i = 0; i < 12; i++) {
            acc[i] = S[i]; acc[12 + i] = Tx[i]; acc[24 + i] = Ty[i]; acc[36 + i] = Tz[i];
        }
#pragma unroll
        for (int k = 0; k < 48; k++) acc[k] = waveReduceAdd(acc[k]);
        if (lane == 0) {
#pragma unroll
            for (int k = 0; k < 48; k++) sh48[wave][k] = (double)acc[k];
        }
        __syncthreads();
        // wave 0: sharded f64 atomic adds at the coherence point
        if (tid < 48) {
            double bsum = sh48[0][tid] + sh48[1][tid] + sh48[2][tid] + sh48[3][tid];
            (void)__hip_atomic_fetch_add(&g_acc[it][myShard][tid], bsum,
                                         __ATOMIC_RELAXED, __HIP_MEMORY_SCOPE_AGENT);
        }
        if (tid == 0) arriveAndWait(1 + it, target);
        __syncthreads();

        // every block reads the 8 shards (fixed order -> identical f64 result)
        if (tid < 48) {
            double a0 = 0, a1 = 0;
#pragma unroll
            for (int s = 0; s < NSHARD; s += 2) {
                a0 += loadRlxD(&g_acc[it][s][tid]);
                a1 += loadRlxD(&g_acc[it][s + 1][tid]);
            }
            dsumL[tid] = a0 + a1;
        }
        __syncthreads();
        if (tid == 0)
            kabschUpdate(dsumL, QdL, QfL, out, it, bid == 0);
        __syncthreads();
    }
}

extern "C" void kernel_launch(void* const* d_in, const int* in_sizes, int n_in,
                              void* d_out, int out_size, void* d_ws, size_t ws_size,
                              hipStream_t stream) {
    (void)d_ws; (void)ws_size;
    const float* xyz = (const float*)d_in[0];
    const float* zdna = (const float*)d_in[1];
    int N = in_sizes[0] / 81;  // CA at atom index 1 of 27
    float* out = (float*)d_out;

    hipLaunchKernelGGL(k_all, dim3(NBLK), dim3(THREADS), 0, stream,
                       xyz, zdna, out, N);
}

// Round 12
// 305.360 us; speedup vs baseline: 2.9172x; 1.5207x over previous
//
#include <hip/hip_runtime.h>
#include <math.h>

#define NBLK 256
#define THREADS 256
#define PTS 7      // 256*256*7 = 458752 >= 400000
#define NSHARD 8   // cross-block f64 sum shards
#define CPAD 16    // counter pad: one 64B line per counter
#define KORD 5     // Taylor order of exp(2 q.p / C)
#define MORD 6     // moment max total degree = KORD+1
#define NMOM 84    // #monomials deg<=6  (C(9,3))
#define NCON 56    // #monomials deg<=5  (C(8,3))
#define CC 50.000001

// Cross-block state, accessed only via agent-scope atomics/loads/stores
// (round-10-proven primitives). g_cnt is monotonic forever -> replay-safe.
__device__ double g_slot[NBLK][8];         // per-block stats slots (64B rows)
__device__ double g_macc[NSHARD][NMOM];    // sharded f64 moment accumulators
__device__ int g_cnt[2 * CPAD];            // arrival counters (monotonic)

__device__ inline float waveReduceAdd(float v) {
#pragma unroll
    for (int off = 32; off > 0; off >>= 1) v += __shfl_down(v, off, 64);
    return v;
}

__device__ inline int loadRlxI(int* p) {
    return __hip_atomic_load(p, __ATOMIC_RELAXED, __HIP_MEMORY_SCOPE_AGENT);
}
__device__ inline int loadAcqI(int* p) {
    return __hip_atomic_load(p, __ATOMIC_ACQUIRE, __HIP_MEMORY_SCOPE_AGENT);
}
__device__ inline double loadRlxD(double* p) {
    return __hip_atomic_load(p, __ATOMIC_RELAXED, __HIP_MEMORY_SCOPE_AGENT);
}
__device__ inline void storeRlxD(double* p, double v) {
    __hip_atomic_store(p, v, __ATOMIC_RELAXED, __HIP_MEMORY_SCOPE_AGENT);
}

// Thread-0 arrival barrier (round 10, proven): fence, count, relaxed poll,
// one acquire load after the flip.
__device__ inline void arriveAndWait(int slot, int target) {
    __threadfence();
    atomicAdd(&g_cnt[slot * CPAD], 1);
    while (loadRlxI(&g_cnt[slot * CPAD]) < target) __builtin_amdgcn_s_sleep(8);
    (void)loadAcqI(&g_cnt[slot * CPAD]);
}

// Flat index of monomial x^a y^b z^g in the a-major/b/g enumeration of all
// triples with a+b+g <= 6.
__device__ inline int idx6(int a, int b, int g) {
    int off = 0;
    for (int ap = 0; ap < a; ++ap) off += (7 - ap) * (8 - ap) / 2;
    return off + b * (7 - a) - b * (b - 1) / 2 + g;
}

// Serial f64 weighted-Kabsch (bit-identical to rounds 4/7/8/9/10, absmax 0.0).
__device__ void kabschUpdate(const double* __restrict__ dsum,
                             double (*Qd)[3], float (*Qf)[3],
                             float* __restrict__ out, int it) {
    double S[12], Tv[12][3], Q[12][3];
    for (int i = 0; i < 12; i++) {
        S[i] = dsum[i];
        Tv[i][0] = dsum[12 + i];
        Tv[i][1] = dsum[24 + i];
        Tv[i][2] = dsum[36 + i];
        for (int c = 0; c < 3; c++) Q[i][c] = Qd[i][c];
    }
    double n[12], wsum = 0;
    for (int i = 0; i < 12; i++) {
        n[i] = 1.0 / (S[i] + 1e-6);
        wsum += S[i] * n[i];
    }
    wsum = fmax(wsum, 1e-6);
    double cP[3] = {0, 0, 0}, cQ[3] = {0, 0, 0};
    for (int i = 0; i < 12; i++)
        for (int c = 0; c < 3; c++) {
            cP[c] += n[i] * Tv[i][c];
            cQ[c] += S[i] * n[i] * Q[i][c];
        }
    for (int c = 0; c < 3; c++) { cP[c] /= wsum; cQ[c] /= wsum; }

    double H[3][3] = {{0, 0, 0}, {0, 0, 0}, {0, 0, 0}};
    for (int i = 0; i < 12; i++) {
        double ta[3];
        for (int a = 0; a < 3; a++) ta[a] = n[i] * (Tv[i][a] - S[i] * cP[a]);
        for (int a = 0; a < 3; a++)
            for (int b = 0; b < 3; b++) H[a][b] += ta[a] * (Q[i][b] - cQ[b]);
    }
    for (int a = 0; a < 3; a++) H[a][a] += 1e-6;

    double A[3][3], V[3][3];
    for (int a = 0; a < 3; a++)
        for (int b = 0; b < 3; b++) {
            double s = 0;
            for (int k = 0; k < 3; k++) s += H[k][a] * H[k][b];
            A[a][b] = s;
            V[a][b] = (a == b) ? 1.0 : 0.0;
        }
    for (int sweep = 0; sweep < 8; sweep++) {
        for (int p = 0; p < 2; p++)
            for (int q = p + 1; q < 3; q++) {
                double apq = A[p][q];
                if (fabs(apq) < 1e-12 * (fabs(A[p][p]) + fabs(A[q][q]))) continue;
                double theta = (A[q][q] - A[p][p]) / (2.0 * apq);
                double t = copysign(1.0, theta) / (fabs(theta) + sqrt(theta * theta + 1.0));
                double c = 1.0 / sqrt(t * t + 1.0);
                double s = t * c;
                A[p][p] = A[p][p] - t * apq;
                A[q][q] = A[q][q] + t * apq;
                A[p][q] = 0; A[q][p] = 0;
                int r = 3 - p - q;
                double arp = A[r][p], arq = A[r][q];
                A[r][p] = A[p][r] = c * arp - s * arq;
                A[r][q] = A[q][r] = s * arp + c * arq;
                for (int k = 0; k < 3; k++) {
                    double vkp = V[k][p], vkq = V[k][q];
                    V[k][p] = c * vkp - s * vkq;
                    V[k][q] = s * vkp + c * vkq;
                }
            }
    }
    double U[3][3];
    for (int k = 0; k < 3; k++) {
        double sig = sqrt(fmax(A[k][k], 0.0));
        double u[3];
        for (int a = 0; a < 3; a++)
            u[a] = H[a][0] * V[0][k] + H[a][1] * V[1][k] + H[a][2] * V[2][k];
        double invsig = 1.0 / fmax(sig, 1e-30);
        for (int a = 0; a < 3; a++) U[a][k] = u[a] * invsig;
    }
    double R[3][3];
    for (int a = 0; a < 3; a++)
        for (int b = 0; b < 3; b++)
            R[a][b] = V[a][0] * U[b][0] + V[a][1] * U[b][1] + V[a][2] * U[b][2];
    double det = R[0][0] * (R[1][1] * R[2][2] - R[1][2] * R[2][1])
               - R[0][1] * (R[1][0] * R[2][2] - R[1][2] * R[2][0])
               + R[0][2] * (R[1][0] * R[2][1] - R[1][1] * R[2][0]);
    if (det < 0)
        for (int a = 0; a < 3; a++)
            for (int b = 0; b < 3; b++) R[a][b] = -R[a][b];
    double tr[3];
    for (int b = 0; b < 3; b++)
        tr[b] = cQ[b] - (cP[0] * R[0][b] + cP[1] * R[1][b] + cP[2] * R[2][b]);

    double res2 = 0;
    for (int i = 0; i < 12; i++) {
        double qn[3];
        for (int b = 0; b < 3; b++) {
            qn[b] = Q[i][0] * R[0][b] + Q[i][1] * R[1][b] + Q[i][2] * R[2][b] + tr[b];
            double diff = qn[b] - n[i] * Tv[i][b];
            res2 += diff * diff;
        }
        for (int b = 0; b < 3; b++) {
            Qd[i][b] = qn[b];
            Qf[i][b] = (float)qn[b];
        }
    }
    if (it == 9) {
        double rmsd = sqrt(res2 / 12.0 + 1e-6);
        out[0] = (float)(-10.0 * rmsd);
    }
}

__global__ void __launch_bounds__(THREADS)
k_all(const float* __restrict__ xyz, const float* __restrict__ zdna,
      float* __restrict__ out, int N) {
    const int tid = threadIdx.x, bid = blockIdx.x;
    const int gid = bid * THREADS + tid;
    const int gsz = NBLK * THREADS;
    const int wave = tid >> 6, lane = tid & 63;

    __shared__ int s_base;
    __shared__ double shPart[4][NMOM];
    __shared__ double red8[8][6];
    __shared__ double Md[NMOM];
    __shared__ double coefL[NCON];
    __shared__ int lutL[4][NCON];
    __shared__ double lds48[48];
    __shared__ double QdL[12][3];
    __shared__ float QfL[12][3];
    __shared__ float s_mean[3], s_inv;

    // Monotonic counter base (round-10-proven): counter 1 cannot advance until
    // every block passed barrier 0, which follows every block's entry read.
    if (tid == 0) s_base = loadRlxI(&g_cnt[CPAD]);
    __syncthreads();
    const int target = s_base + NBLK;

    // ---- Phase 1: strided CA load into registers + column stats ----
    float px[PTS], py[PTS], pz[PTS];
    float s0 = 0, s1 = 0, s2 = 0, q0 = 0, q1 = 0, q2 = 0;
#pragma unroll
    for (int k = 0; k < PTS; k++) {
        int j = gid + k * gsz;
        px[k] = 0.0f; py[k] = 0.0f; pz[k] = 0.0f;
        if (j < N) {
            size_t b = (size_t)j * 81 + 3;
            float x = xyz[b + 0], y = xyz[b + 1], z = xyz[b + 2];
            px[k] = x; py[k] = y; pz[k] = z;
            s0 += x; s1 += y; s2 += z;
            q0 += x * x; q1 += y * y; q2 += z * z;
        }
    }
    {
        float v[6] = {s0, s1, s2, q0, q1, q2};
#pragma unroll
        for (int k = 0; k < 6; k++) v[k] = waveReduceAdd(v[k]);
        if (lane == 0) {
#pragma unroll
            for (int k = 0; k < 6; k++) shPart[wave][k] = (double)v[k];
        }
        __syncthreads();
        if (tid < 6)
            storeRlxD(&g_slot[bid][tid],
                      shPart[0][tid] + shPart[1][tid] + shPart[2][tid] + shPart[3][tid]);
        // zero this call's moment shards (blocks 0..7 x 84 components)
        if (bid < NSHARD && tid < NMOM) storeRlxD(&g_macc[bid][tid], 0.0);
        if (tid < NMOM) __threadfence();  // drain each storer's own sc1 stores
        __syncthreads();
        if (tid == 0) arriveAndWait(0, target);
        __syncthreads();
    }

    // ---- Phase 2 (every block, redundant): mean/std + zdna normalize ----
    {
        if (tid < 48) {
            int col = tid % 6, seg = tid / 6;  // 8 segs x 32 blocks
            double a0 = 0, a1 = 0;
            for (int b2 = seg * 32; b2 < seg * 32 + 32; b2 += 2) {
                a0 += loadRlxD(&g_slot[b2][col]);
                a1 += loadRlxD(&g_slot[b2 + 1][col]);
            }
            red8[seg][col] = a0 + a1;
        }
        __syncthreads();
        if (tid == 0) {
            double tot[6];
            for (int c = 0; c < 6; c++) {
                double s = 0;
                for (int g = 0; g < 8; g++) s += red8[g][c];
                tot[c] = s;
            }
            double mean[3], stdsum = 0;
            for (int c = 0; c < 3; c++) {
                mean[c] = tot[c] / (double)N;
                double var = (tot[3 + c] - (double)N * mean[c] * mean[c]) / (double)(N - 1);
                stdsum += sqrt(fmax(var, 0.0));
            }
            double sdev = fmax(stdsum / 3.0, 1e-6);
            s_mean[0] = (float)mean[0];
            s_mean[1] = (float)mean[1];
            s_mean[2] = (float)mean[2];
            s_inv = (float)(1.0 / sdev);

            double z[12][3], zm[3] = {0, 0, 0};
            for (int i = 0; i < 12; i++)
                for (int c = 0; c < 3; c++) {
                    z[i][c] = (double)zdna[i * 3 + c];
                    zm[c] += z[i][c];
                }
            for (int c = 0; c < 3; c++) zm[c] /= 12.0;
            double zvar[3] = {0, 0, 0};
            for (int i = 0; i < 12; i++)
                for (int c = 0; c < 3; c++) {
                    z[i][c] -= zm[c];
                    zvar[c] += z[i][c] * z[i][c];
                }
            double zs = 0;
            for (int c = 0; c < 3; c++) zs += sqrt(zvar[c] / 11.0);
            zs = fmax(zs / 3.0, 1e-6);
            double zinv = 1.0 / zs;
            for (int i = 0; i < 12; i++)
                for (int c = 0; c < 3; c++) {
                    double q = z[i][c] * zinv;
                    QdL[i][c] = q;
                    QfL[i][c] = (float)q;
                }
        }
        __syncthreads();
    }

    // ---- normalize register-resident points ----
    {
        float mx = s_mean[0], my = s_mean[1], mz = s_mean[2];
        float inv = s_inv;
#pragma unroll
        for (int k = 0; k < PTS; k++) {
            px[k] = (px[k] - mx) * inv;
            py[k] = (py[k] - my) * inv;
            pz[k] = (pz[k] - mz) * inv;
        }
    }

    // ---- Phase 3: weighted moments M[a,b,g] = sum_j e^{-|p|^2/C} x^a y^b z^g
    {
        float mom[NMOM];
#pragma unroll
        for (int k = 0; k < NMOM; k++) mom[k] = 0.0f;
#pragma unroll
        for (int k = 0; k < PTS; k++) {
            if (gid + k * gsz < N) {
                float x = px[k], y = py[k], z = pz[k];
                float pp = x * x + y * y + z * z;
                float w0 = __expf(-pp * (float)(1.0 / CC));
                float ta = w0;
                int m = 0;
#pragma unroll
                for (int a = 0; a <= MORD; ++a) {
                    float tb = ta;
#pragma unroll
                    for (int b = 0; b <= MORD - a; ++b) {
                        float tc = tb;
#pragma unroll
                        for (int g = 0; g <= MORD - a - b; ++g) {
                            mom[m] += tc;  // m is compile-time after unroll
                            tc *= z;
                            ++m;
                        }
                        tb *= y;
                    }
                    ta *= x;
                }
            }
        }
#pragma unroll
        for (int k = 0; k < NMOM; k++) mom[k] = waveReduceAdd(mom[k]);
        if (lane == 0) {
#pragma unroll
            for (int k = 0; k < NMOM; k++) shPart[wave][k] = (double)mom[k];
        }
        __syncthreads();
        if (tid < NMOM) {
            double s = shPart[0][tid] + shPart[1][tid] + shPart[2][tid] + shPart[3][tid];
            (void)__hip_atomic_fetch_add(&g_macc[bid & (NSHARD - 1)][tid], s,
                                         __ATOMIC_RELAXED, __HIP_MEMORY_SCOPE_AGENT);
            __threadfence();  // ensure this thread's atomic completed
        }
        __syncthreads();
    }

    // Blocks != 0: arrive at barrier 1 and exit. Block 0 waits, then iterates.
    if (bid != 0) {
        if (tid == 0) {
            __threadfence();
            atomicAdd(&g_cnt[CPAD], 1);
        }
        return;
    }
    if (tid == 0) arriveAndWait(1, target);
    __syncthreads();

    // ---- Phase 4 (block 0 only): combine shards; build coef/LUT ----
    if (tid < NMOM) {
        double s = 0;
#pragma unroll
        for (int s8 = 0; s8 < NSHARD; ++s8) s += loadRlxD(&g_macc[s8][tid]);
        Md[tid] = s;
    }
    if (tid == 64) {  // wave 1: overlap with Md sums
        int m = 0;
        for (int a = 0; a <= KORD; ++a)
            for (int b = 0; b <= KORD - a; ++b)
                for (int g = 0; g <= KORD - a - b; ++g) {
                    double c = 1.0;
                    for (int t = 0; t < a + b + g; ++t) c *= 2.0 / CC;
                    for (int t = 2; t <= a; ++t) c /= (double)t;
                    for (int t = 2; t <= b; ++t) c /= (double)t;
                    for (int t = 2; t <= g; ++t) c /= (double)t;
                    coefL[m] = c;
                    lutL[0][m] = idx6(a, b, g);
                    lutL[1][m] = idx6(a + 1, b, g);
                    lutL[2][m] = idx6(a, b + 1, g);
                    lutL[3][m] = idx6(a, b, g + 1);
                    ++m;
                }
    }
    __syncthreads();

    // ---- 10 iterations, fully local to block 0 ----
    for (int it = 0; it < 10; ++it) {
        if (tid < 48) {
            int i = tid >> 2, comp = tid & 3;  // comp: 0=S 1=Tx 2=Ty 3=Tz
            double qx = (double)QfL[i][0];
            double qy = (double)QfL[i][1];
            double qz = (double)QfL[i][2];
            double acc = 0.0;
            int m = 0;
            double xa = 1.0;
            for (int a = 0; a <= KORD; ++a) {
                double yb = xa;
                for (int b = 0; b <= KORD - a; ++b) {
                    double zg = yb;
                    for (int g = 0; g <= KORD - a - b; ++g) {
                        acc += coefL[m] * zg * Md[lutL[comp][m]];
                        zg *= qz;
                        ++m;
                    }
                    yb *= qy;
                }
                xa *= qx;
            }
            double qq = qx * qx + qy * qy + qz * qz;
            lds48[comp * 12 + i] = exp(-qq / CC) * acc;
        }
        __syncthreads();
        if (tid == 0) kabschUpdate(lds48, QdL, QfL, out, it);
        __syncthreads();
    }
}

extern "C" void kernel_launch(void* const* d_in, const int* in_sizes, int n_in,
                              void* d_out, int out_size, void* d_ws, size_t ws_size,
                              hipStream_t stream) {
    (void)d_ws; (void)ws_size;
    const float* xyz = (const float*)d_in[0];
    const float* zdna = (const float*)d_in[1];
    int N = in_sizes[0] / 81;  // CA at atom index 1 of 27
    float* out = (float*)d_out;

    hipLaunchKernelGGL(k_all, dim3(NBLK), dim3(THREADS), 0, stream,
                       xyz, zdna, out, N);
}

// Round 13
// 274.271 us; speedup vs baseline: 3.2479x; 1.1133x over previous
//
#include <hip/hip_runtime.h>
#include <math.h>

#define THREADS 256
#define NBLK 256
#define MAX_N 400000
#define NSHARD 8   // f64 moment-accumulator shards (32 atomic adds/address)
#define KORD 5     // Taylor order of exp(2 q.p / C)
#define MORD 6     // moment max total degree = KORD+1
#define NMOM 84    // #monomials deg<=6  (C(9,3))
#define NCON 56    // #monomials deg<=5  (C(8,3))
#define CC 50.000001

// Cross-kernel state in device globals. Written in K1/K2, read in K2/K3 —
// dispatch-boundary coherence proven in rounds 4/7. No ws_size dependence;
// everything read is written earlier in the same kernel_launch call.
__device__ float g_cax[MAX_N], g_cay[MAX_N], g_caz[MAX_N];
__device__ double g_slot[NBLK][8];        // per-block stats (64B rows)
__device__ double g_macc[NSHARD][NMOM];   // sharded f64 moment accumulators

__device__ inline float waveReduceAdd(float v) {
#pragma unroll
    for (int off = 32; off > 0; off >>= 1) v += __shfl_down(v, off, 64);
    return v;
}

// Flat index of monomial x^a y^b z^g in the a-major/b/g enumeration (deg<=6).
__device__ inline int idx6(int a, int b, int g) {
    int off = 0;
    for (int ap = 0; ap < a; ++ap) off += (7 - ap) * (8 - ap) / 2;
    return off + b * (7 - a) - b * (b - 1) / 2 + g;
}

// Serial f64 weighted-Kabsch (byte-identical to the round-12 verified tail).
__device__ void kabschUpdate(const double* __restrict__ dsum,
                             double (*Qd)[3], float (*Qf)[3],
                             float* __restrict__ out, int it) {
    double S[12], Tv[12][3], Q[12][3];
    for (int i = 0; i < 12; i++) {
        S[i] = dsum[i];
        Tv[i][0] = dsum[12 + i];
        Tv[i][1] = dsum[24 + i];
        Tv[i][2] = dsum[36 + i];
        for (int c = 0; c < 3; c++) Q[i][c] = Qd[i][c];
    }
    double n[12], wsum = 0;
    for (int i = 0; i < 12; i++) {
        n[i] = 1.0 / (S[i] + 1e-6);
        wsum += S[i] * n[i];
    }
    wsum = fmax(wsum, 1e-6);
    double cP[3] = {0, 0, 0}, cQ[3] = {0, 0, 0};
    for (int i = 0; i < 12; i++)
        for (int c = 0; c < 3; c++) {
            cP[c] += n[i] * Tv[i][c];
            cQ[c] += S[i] * n[i] * Q[i][c];
        }
    for (int c = 0; c < 3; c++) { cP[c] /= wsum; cQ[c] /= wsum; }

    double H[3][3] = {{0, 0, 0}, {0, 0, 0}, {0, 0, 0}};
    for (int i = 0; i < 12; i++) {
        double ta[3];
        for (int a = 0; a < 3; a++) ta[a] = n[i] * (Tv[i][a] - S[i] * cP[a]);
        for (int a = 0; a < 3; a++)
            for (int b = 0; b < 3; b++) H[a][b] += ta[a] * (Q[i][b] - cQ[b]);
    }
    for (int a = 0; a < 3; a++) H[a][a] += 1e-6;

    double A[3][3], V[3][3];
    for (int a = 0; a < 3; a++)
        for (int b = 0; b < 3; b++) {
            double s = 0;
            for (int k = 0; k < 3; k++) s += H[k][a] * H[k][b];
            A[a][b] = s;
            V[a][b] = (a == b) ? 1.0 : 0.0;
        }
    for (int sweep = 0; sweep < 8; sweep++) {
        for (int p = 0; p < 2; p++)
            for (int q = p + 1; q < 3; q++) {
                double apq = A[p][q];
                if (fabs(apq) < 1e-12 * (fabs(A[p][p]) + fabs(A[q][q]))) continue;
                double theta = (A[q][q] - A[p][p]) / (2.0 * apq);
                double t = copysign(1.0, theta) / (fabs(theta) + sqrt(theta * theta + 1.0));
                double c = 1.0 / sqrt(t * t + 1.0);
                double s = t * c;
                A[p][p] = A[p][p] - t * apq;
                A[q][q] = A[q][q] + t * apq;
                A[p][q] = 0; A[q][p] = 0;
                int r = 3 - p - q;
                double arp = A[r][p], arq = A[r][q];
                A[r][p] = A[p][r] = c * arp - s * arq;
                A[r][q] = A[q][r] = s * arp + c * arq;
                for (int k = 0; k < 3; k++) {
                    double vkp = V[k][p], vkq = V[k][q];
                    V[k][p] = c * vkp - s * vkq;
                    V[k][q] = s * vkp + c * vkq;
                }
            }
    }
    double U[3][3];
    for (int k = 0; k < 3; k++) {
        double sig = sqrt(fmax(A[k][k], 0.0));
        double u[3];
        for (int a = 0; a < 3; a++)
            u[a] = H[a][0] * V[0][k] + H[a][1] * V[1][k] + H[a][2] * V[2][k];
        double invsig = 1.0 / fmax(sig, 1e-30);
        for (int a = 0; a < 3; a++) U[a][k] = u[a] * invsig;
    }
    double R[3][3];
    for (int a = 0; a < 3; a++)
        for (int b = 0; b < 3; b++)
            R[a][b] = V[a][0] * U[b][0] + V[a][1] * U[b][1] + V[a][2] * U[b][2];
    double det = R[0][0] * (R[1][1] * R[2][2] - R[1][2] * R[2][1])
               - R[0][1] * (R[1][0] * R[2][2] - R[1][2] * R[2][0])
               + R[0][2] * (R[1][0] * R[2][1] - R[1][1] * R[2][0]);
    if (det < 0)
        for (int a = 0; a < 3; a++)
            for (int b = 0; b < 3; b++) R[a][b] = -R[a][b];
    double tr[3];
    for (int b = 0; b < 3; b++)
        tr[b] = cQ[b] - (cP[0] * R[0][b] + cP[1] * R[1][b] + cP[2] * R[2][b]);

    double res2 = 0;
    for (int i = 0; i < 12; i++) {
        double qn[3];
        for (int b = 0; b < 3; b++) {
            qn[b] = Q[i][0] * R[0][b] + Q[i][1] * R[1][b] + Q[i][2] * R[2][b] + tr[b];
            double diff = qn[b] - n[i] * Tv[i][b];
            res2 += diff * diff;
        }
        for (int b = 0; b < 3; b++) {
            Qd[i][b] = qn[b];
            Qf[i][b] = (float)qn[b];
        }
    }
    if (it == 9) {
        double rmsd = sqrt(res2 / 12.0 + 1e-6);
        out[0] = (float)(-10.0 * rmsd);
    }
}

// K1: strided CA extract -> planar g_ca*, per-block stats, zero shards.
__global__ void __launch_bounds__(THREADS)
k_extract(const float* __restrict__ xyz, int N, int chunk) {
    const int tid = threadIdx.x, bid = blockIdx.x;
    const int start = bid * chunk;
    const int lim = (start + chunk < N) ? (start + chunk) : N;
    const int wave = tid >> 6, lane = tid & 63;

    float s0 = 0, s1 = 0, s2 = 0, q0 = 0, q1 = 0, q2 = 0;
    for (int j = start + tid; j < lim; j += THREADS) {
        size_t b = (size_t)j * 81 + 3;
        float x = xyz[b + 0], y = xyz[b + 1], z = xyz[b + 2];
        g_cax[j] = x; g_cay[j] = y; g_caz[j] = z;
        s0 += x; s1 += y; s2 += z;
        q0 += x * x; q1 += y * y; q2 += z * z;
    }
    __shared__ double p6[4][6];
    float v[6] = {s0, s1, s2, q0, q1, q2};
#pragma unroll
    for (int k = 0; k < 6; k++) v[k] = waveReduceAdd(v[k]);
    if (lane == 0) {
#pragma unroll
        for (int k = 0; k < 6; k++) p6[wave][k] = (double)v[k];
    }
    __syncthreads();
    if (tid < 6)
        g_slot[bid][tid] = p6[0][tid] + p6[1][tid] + p6[2][tid] + p6[3][tid];
    // zero this call's moment shards (threads 64..147 to spread the work)
    if (bid < NSHARD && tid >= 64 && tid < 64 + NMOM)
        g_macc[bid][tid - 64] = 0.0;
}

// K2: redundant stats-reduce -> normalize -> weighted moments -> shard atomics.
__global__ void __launch_bounds__(THREADS)
k_moments(int N, int chunk) {
    const int tid = threadIdx.x, bid = blockIdx.x;
    const int wave = tid >> 6, lane = tid & 63;
    __shared__ double red8[8][6];
    __shared__ float s_mean[3], s_inv;
    __shared__ double shPart[4][NMOM];

    if (tid < 48) {
        int col = tid % 6, seg = tid / 6;  // 8 segs x 32 blocks
        double a0 = 0, a1 = 0;
        for (int b2 = seg * 32; b2 < seg * 32 + 32; b2 += 2) {
            a0 += g_slot[b2][col];
            a1 += g_slot[b2 + 1][col];
        }
        red8[seg][col] = a0 + a1;
    }
    __syncthreads();
    if (tid == 0) {
        double tot[6];
        for (int c = 0; c < 6; c++) {
            double s = 0;
            for (int g = 0; g < 8; g++) s += red8[g][c];
            tot[c] = s;
        }
        double mean[3], stdsum = 0;
        for (int c = 0; c < 3; c++) {
            mean[c] = tot[c] / (double)N;
            double var = (tot[3 + c] - (double)N * mean[c] * mean[c]) / (double)(N - 1);
            stdsum += sqrt(fmax(var, 0.0));
        }
        double sdev = fmax(stdsum / 3.0, 1e-6);
        s_mean[0] = (float)mean[0];
        s_mean[1] = (float)mean[1];
        s_mean[2] = (float)mean[2];
        s_inv = (float)(1.0 / sdev);
    }
    __syncthreads();

    const float mx = s_mean[0], my = s_mean[1], mz = s_mean[2];
    const float inv = s_inv;
    const int start = bid * chunk;
    const int lim = (start + chunk < N) ? (start + chunk) : N;

    float mom[NMOM];
#pragma unroll
    for (int k = 0; k < NMOM; k++) mom[k] = 0.0f;
    for (int j = start + tid; j < lim; j += THREADS) {
        float x = (g_cax[j] - mx) * inv;
        float y = (g_cay[j] - my) * inv;
        float z = (g_caz[j] - mz) * inv;
        float pp = x * x + y * y + z * z;
        float w0 = __expf(-pp * (float)(1.0 / CC));
        float ta = w0;
        int m = 0;
#pragma unroll
        for (int a = 0; a <= MORD; ++a) {
            float tb = ta;
#pragma unroll
            for (int b = 0; b <= MORD - a; ++b) {
                float tc = tb;
#pragma unroll
                for (int g = 0; g <= MORD - a - b; ++g) {
                    mom[m] += tc;  // m compile-time after full unroll
                    tc *= z;
                    ++m;
                }
                tb *= y;
            }
            ta *= x;
        }
    }
#pragma unroll
    for (int k = 0; k < NMOM; k++) mom[k] = waveReduceAdd(mom[k]);
    if (lane == 0) {
#pragma unroll
        for (int k = 0; k < NMOM; k++) shPart[wave][k] = (double)mom[k];
    }
    __syncthreads();
    if (tid < NMOM) {
        double s = shPart[0][tid] + shPart[1][tid] + shPart[2][tid] + shPart[3][tid];
        (void)__hip_atomic_fetch_add(&g_macc[bid & (NSHARD - 1)][tid], s,
                                     __ATOMIC_RELAXED, __HIP_MEMORY_SCOPE_AGENT);
    }
}

// K3 (1 block): combine shards, LUT, zdna init, 10 local iterations.
__global__ void __launch_bounds__(THREADS)
k_iters(const float* __restrict__ zdna, float* __restrict__ out, int N) {
    const int tid = threadIdx.x;
    __shared__ double Md[NMOM];
    __shared__ double coefL[NCON];
    __shared__ int lutL[4][NCON];
    __shared__ double lds48[48];
    __shared__ double QdL[12][3];
    __shared__ float QfL[12][3];

    if (tid < NMOM) {
        double s = 0;
#pragma unroll
        for (int s8 = 0; s8 < NSHARD; ++s8) s += g_macc[s8][tid];
        Md[tid] = s;
    }
    if (tid == 128) {  // wave 2: Taylor coefficients + moment-index LUT
        int m = 0;
        for (int a = 0; a <= KORD; ++a)
            for (int b = 0; b <= KORD - a; ++b)
                for (int g = 0; g <= KORD - a - b; ++g) {
                    double c = 1.0;
                    for (int t = 0; t < a + b + g; ++t) c *= 2.0 / CC;
                    for (int t = 2; t <= a; ++t) c /= (double)t;
                    for (int t = 2; t <= b; ++t) c /= (double)t;
                    for (int t = 2; t <= g; ++t) c /= (double)t;
                    coefL[m] = c;
                    lutL[0][m] = idx6(a, b, g);
                    lutL[1][m] = idx6(a + 1, b, g);
                    lutL[2][m] = idx6(a, b + 1, g);
                    lutL[3][m] = idx6(a, b, g + 1);
                    ++m;
                }
    }
    if (tid == 192) {  // wave 3: zdna normalize -> Q0 (independent of binder)
        double z[12][3], zm[3] = {0, 0, 0};
        for (int i = 0; i < 12; i++)
            for (int c = 0; c < 3; c++) {
                z[i][c] = (double)zdna[i * 3 + c];
                zm[c] += z[i][c];
            }
        for (int c = 0; c < 3; c++) zm[c] /= 12.0;
        double zvar[3] = {0, 0, 0};
        for (int i = 0; i < 12; i++)
            for (int c = 0; c < 3; c++) {
                z[i][c] -= zm[c];
                zvar[c] += z[i][c] * z[i][c];
            }
        double zs = 0;
        for (int c = 0; c < 3; c++) zs += sqrt(zvar[c] / 11.0);
        zs = fmax(zs / 3.0, 1e-6);
        double zinv = 1.0 / zs;
        for (int i = 0; i < 12; i++)
            for (int c = 0; c < 3; c++) {
                double q = z[i][c] * zinv;
                QdL[i][c] = q;
                QfL[i][c] = (float)q;
            }
    }
    __syncthreads();

    for (int it = 0; it < 10; ++it) {
        if (tid < 48) {
            int i = tid >> 2, comp = tid & 3;  // 0=S 1=Tx 2=Ty 3=Tz
            double qx = (double)QfL[i][0];
            double qy = (double)QfL[i][1];
            double qz = (double)QfL[i][2];
            double acc = 0.0;
            int m = 0;
            double xa = 1.0;
            for (int a = 0; a <= KORD; ++a) {
                double yb = xa;
                for (int b = 0; b <= KORD - a; ++b) {
                    double zg = yb;
                    for (int g = 0; g <= KORD - a - b; ++g) {
                        acc += coefL[m] * zg * Md[lutL[comp][m]];
                        zg *= qz;
                        ++m;
                    }
                    yb *= qy;
                }
                xa *= qx;
            }
            double qq = qx * qx + qy * qy + qz * qz;
            lds48[comp * 12 + i] = exp(-qq / CC) * acc;
        }
        __syncthreads();
        if (tid == 0) kabschUpdate(lds48, QdL, QfL, out, it);
        __syncthreads();
    }
}

extern "C" void kernel_launch(void* const* d_in, const int* in_sizes, int n_in,
                              void* d_out, int out_size, void* d_ws, size_t ws_size,
                              hipStream_t stream) {
    (void)d_ws; (void)ws_size;
    const float* xyz = (const float*)d_in[0];
    const float* zdna = (const float*)d_in[1];
    int N = in_sizes[0] / 81;  // CA at atom index 1 of 27
    int chunk = (N + NBLK - 1) / NBLK;
    float* out = (float*)d_out;

    hipLaunchKernelGGL(k_extract, dim3(NBLK), dim3(THREADS), 0, stream,
                       xyz, N, chunk);
    hipLaunchKernelGGL(k_moments, dim3(NBLK), dim3(THREADS), 0, stream,
                       N, chunk);
    hipLaunchKernelGGL(k_iters, dim3(1), dim3(THREADS), 0, stream,
                       zdna, out, N);
}